// Round 5
// baseline (85.172 us; speedup 1.0000x reference)
//
#include <hip/hip_runtime.h>

#define Bn 2
#define Nn 4096
#define Cn 256
#define Kn 64
#define BK (Bn * Kn)
#define CHUNKS 32                    // chunks per batch
#define CROWS (Nn / CHUNKS)          // 128 rows per chunk
#define NBLK1 (Bn * CHUNKS)          // 64 blocks in kernel 1

// Order-preserving float->uint encoding: a >= b  <=>  enc(a) >= enc(b).
// 0u is below every real encoding -> doubles as the "empty" sentinel.
__device__ __forceinline__ unsigned enc_f32(float x) {
    const unsigned b = __float_as_uint(x);
    return (b & 0x80000000u) ? ~b : (b | 0x80000000u);
}
__device__ __forceinline__ float dec_f32(unsigned e) {
    return __uint_as_float((e & 0x80000000u) ? (e & 0x7FFFFFFFu) : ~e);
}

// ---------------- Kernel 1: stream features once, scatter-max into LDS ----
// grid = (Bn*CHUNKS) blocks, 1024 threads. Block = (batch b, row-chunk).
// Lane l owns box l (K=64 == wavefront). Per row: ballot of box membership,
// then LDS atomicMax (encoded) into acc[box][ch], lane l on ch {l,l+64,...}
// so the 64 lanes hit 64 consecutive u32 -> conflict-free banks.
__global__ __launch_bounds__(1024) void pool_stream_kernel(
    const float* __restrict__ points,      // (B,N,3)
    const float* __restrict__ feats,       // (B,N,C)
    const float* __restrict__ proposals,   // (B,K,7)
    unsigned* __restrict__ partial)        // (NBLK1, 64, 256) encoded
{
    const int blk   = blockIdx.x;
    const int b     = blk >> 5;            // batch
    const int chunk = blk & (CHUNKS - 1);
    const int tid   = threadIdx.x;
    const int w     = tid >> 6;            // wave 0..15
    const int lane  = tid & 63;
    const int base  = chunk * CROWS;

    __shared__ unsigned s_acc[Kn * Cn];    // 64 KB encoded maxima
    __shared__ float    s_pts[CROWS * 3];  // 1.5 KB chunk points

    // init acc to bottom
    #pragma unroll
    for (int i = tid; i < Kn * Cn; i += 1024) s_acc[i] = 0u;
    // stage this chunk's point coords
    if (tid < CROWS * 3)
        s_pts[tid] = points[(size_t)b * Nn * 3 + base * 3 + tid];

    // lane l's box bounds
    const float* prop = proposals + ((size_t)b * Kn + lane) * 7;
    const float cx = prop[0], cy = prop[1], cz = prop[2];
    const float hx = prop[3] * 0.5f, hy = prop[4] * 0.5f, hz = prop[5] * 0.5f;
    const float lox = cx - hx, loy = cy - hy, loz = cz - hz;
    const float hix = cx + hx, hiy = cy + hy, hiz = cz + hz;
    __syncthreads();

    // wave w streams rows base+w, +16, ... (8 rows, all loads in flight).
    // lane l loads ch {l, l+64, l+128, l+192} of each row (coalesced 256B).
    const float* fb = feats + (size_t)b * Nn * Cn;
    float f[8][4];
    #pragma unroll
    for (int j = 0; j < 8; ++j) {
        const size_t r = (size_t)(base + w + 16 * j) * Cn;
        #pragma unroll
        for (int c = 0; c < 4; ++c)
            f[j][c] = fb[r + c * 64 + lane];
    }

    #pragma unroll
    for (int j = 0; j < 8; ++j) {
        const int lr = w + 16 * j;
        const float px = s_pts[lr * 3 + 0];
        const float py = s_pts[lr * 3 + 1];
        const float pz = s_pts[lr * 3 + 2];
        const bool in = (px > lox) & (px < hix) &
                        (py > loy) & (py < hiy) &
                        (pz > loz) & (pz < hiz);
        unsigned long long mask = __ballot(in);   // uniform across wave
        if (mask) {
            const unsigned e0 = enc_f32(f[j][0]);
            const unsigned e1 = enc_f32(f[j][1]);
            const unsigned e2 = enc_f32(f[j][2]);
            const unsigned e3 = enc_f32(f[j][3]);
            while (mask) {
                const int k = (int)__builtin_ctzll(mask);
                mask &= mask - 1;
                atomicMax(&s_acc[k * Cn +   0 + lane], e0);
                atomicMax(&s_acc[k * Cn +  64 + lane], e1);
                atomicMax(&s_acc[k * Cn + 128 + lane], e2);
                atomicMax(&s_acc[k * Cn + 192 + lane], e3);
            }
        }
    }
    __syncthreads();

    // write the block's partial (still encoded), vectorized
    uint4* po = (uint4*)(partial + (size_t)blk * Kn * Cn);
    const uint4* pa = (const uint4*)s_acc;
    #pragma unroll
    for (int i = tid; i < Kn * Cn / 4; i += 1024) po[i] = pa[i];
}

// ---------------- Kernel 2: reduce partials + decode + 2-layer MLP --------
// grid = 128 (one per box), 1024 threads, c-split-4 MLP (proven in R2).
__global__ __launch_bounds__(1024) void reduce_mlp_kernel(
    const unsigned* __restrict__ partial,  // (NBLK1, 64, 256)
    const float* __restrict__ W1,          // (C,256)
    const float* __restrict__ b1,
    const float* __restrict__ W2,          // (256,256)
    const float* __restrict__ b2,
    float* __restrict__ out)               // (B,K,256)
{
    const int bk  = blockIdx.x;
    const int b   = bk >> 6;
    const int k   = bk & 63;
    const int tid = threadIdx.x;
    const int g   = tid >> 8;              // 0..3
    const int ch  = tid & 255;

    __shared__ unsigned s_m[4][Cn];
    __shared__ float    s_vec[Cn];
    __shared__ float    s_red[4][Cn];

    // each group reduces 8 of the batch's 32 partials
    const unsigned* pp = partial +
        ((size_t)(b * CHUNKS) * Kn + k) * Cn + ch;
    unsigned m = 0u;
    #pragma unroll
    for (int j = 0; j < 8; ++j)
        m = max(m, pp[(size_t)(g * 8 + j) * Kn * Cn]);
    s_m[g][ch] = m;
    __syncthreads();

    if (tid < Cn) {
        const unsigned e = max(max(s_m[0][tid], s_m[1][tid]),
                               max(s_m[2][tid], s_m[3][tid]));
        s_vec[tid] = (e == 0u) ? 0.0f : dec_f32(e);   // empty box -> 0
    }
    __syncthreads();

    // layer 1, c-split 4 ways
    {
        const float* w1 = W1 + (size_t)(g * 64) * 256 + ch;
        const float* sv = s_vec + g * 64;
        float acc = 0.0f;
        #pragma unroll 16
        for (int c = 0; c < 64; ++c)
            acc = fmaf(sv[c], w1[(size_t)c * 256], acc);
        s_red[g][ch] = acc;
    }
    __syncthreads();
    if (tid < Cn) {
        s_vec[tid] = fmaxf(
            b1[tid] + ((s_red[0][tid] + s_red[1][tid]) +
                       (s_red[2][tid] + s_red[3][tid])), 0.0f);
    }
    __syncthreads();

    // layer 2
    {
        const float* w2 = W2 + (size_t)(g * 64) * 256 + ch;
        const float* sv = s_vec + g * 64;
        float acc = 0.0f;
        #pragma unroll 16
        for (int c = 0; c < 64; ++c)
            acc = fmaf(sv[c], w2[(size_t)c * 256], acc);
        s_red[g][ch] = acc;
    }
    __syncthreads();
    if (tid < Cn) {
        out[(size_t)bk * 256 + tid] = fmaxf(
            b2[tid] + ((s_red[0][tid] + s_red[1][tid]) +
                       (s_red[2][tid] + s_red[3][tid])), 0.0f);
    }
}

extern "C" void kernel_launch(void* const* d_in, const int* in_sizes, int n_in,
                              void* d_out, int out_size, void* d_ws, size_t ws_size,
                              hipStream_t stream) {
    const float* points    = (const float*)d_in[0];
    const float* feats     = (const float*)d_in[1];
    const float* proposals = (const float*)d_in[2];
    const float* W1        = (const float*)d_in[3];
    const float* b1        = (const float*)d_in[4];
    const float* W2        = (const float*)d_in[5];
    const float* b2        = (const float*)d_in[6];
    float* out             = (float*)d_out;
    unsigned* partial      = (unsigned*)d_ws;      // 64*64*256*4 = 4 MB

    pool_stream_kernel<<<NBLK1, 1024, 0, stream>>>(points, feats, proposals,
                                                   partial);
    reduce_mlp_kernel<<<BK, 1024, 0, stream>>>(partial, W1, b1, W2, b2, out);
}

// Round 6
// 82.581 us; speedup vs baseline: 1.0314x; 1.0314x over previous
//
#include <hip/hip_runtime.h>

#define Bn 2
#define Nn 4096
#define Cn 256
#define Kn 64
#define BK (Bn * Kn)
#define NW 16             // waves per block
#define BT 1024           // threads per block
#define HALF (Nn / 2)     // 2048 points per k1 block
#define PAD (7 * NW)      // gather batch over-read padding

__device__ __forceinline__ float4 max4(float4 a, float4 b) {
    return make_float4(fmaxf(a.x, b.x), fmaxf(a.y, b.y),
                       fmaxf(a.z, b.z), fmaxf(a.w, b.w));
}

// ---------------- Kernel 1: (box, half) -> 256-float pooled partial -------
// grid = 256 blocks x 1024 thr: full machine during scan+gather; worst-case
// gather chain per wave halves vs the fused 128-block version.
__global__ __launch_bounds__(BT) void pool_half_kernel(
    const float* __restrict__ points,      // (B,N,3)
    const float* __restrict__ feats,       // (B,N,C)
    const float* __restrict__ proposals,   // (B,K,7)
    float* __restrict__ partial)           // (256, 256): -inf when empty
{
    const int blk  = blockIdx.x;
    const int bk   = blk >> 1;             // box 0..127
    const int half = blk & 1;
    const int b    = bk / Kn;
    const int tid  = threadIdx.x;
    const int w    = tid >> 6;             // wave 0..15
    const int lane = tid & 63;

    __shared__ int   s_idx[HALF + PAD];    // 8.6 KB
    __shared__ int   s_count;
    __shared__ float s_part[NW][Cn];       // 16 KB

    // ---- box bounds ----
    const float* prop = proposals + (size_t)bk * 7;
    const float cx = prop[0], cy = prop[1], cz = prop[2];
    const float hx = prop[3] * 0.5f, hy = prop[4] * 0.5f, hz = prop[5] * 0.5f;
    const float lox = cx - hx, loy = cy - hy, loz = cz - hz;
    const float hix = cx + hx, hiy = cy + hy, hiz = cz + hz;

    if (tid == 0) s_count = 0;
    __syncthreads();

    // ---- phase 1: scan this half's 2048 points. Threads 0..511 own 4
    // points each via 3 float4 loads; wave-aggregated compaction
    // (one LDS atomicAdd per wave, ballot/popcount ranking).
    if (tid < 512) {
        const int n0 = half * HALF + 4 * tid;
        const float4* pv = (const float4*)(points + (size_t)b * Nn * 3
                                           + (size_t)half * HALF * 3);
        const float4 q0 = pv[3 * tid + 0];   // x0 y0 z0 x1
        const float4 q1 = pv[3 * tid + 1];   // y1 z1 x2 y2
        const float4 q2 = pv[3 * tid + 2];   // z2 x3 y3 z3

        const bool in0 = (q0.x > lox) & (q0.x < hix) &
                         (q0.y > loy) & (q0.y < hiy) &
                         (q0.z > loz) & (q0.z < hiz);
        const bool in1 = (q0.w > lox) & (q0.w < hix) &
                         (q1.x > loy) & (q1.x < hiy) &
                         (q1.y > loz) & (q1.y < hiz);
        const bool in2 = (q1.z > lox) & (q1.z < hix) &
                         (q1.w > loy) & (q1.w < hiy) &
                         (q2.x > loz) & (q2.x < hiz);
        const bool in3 = (q2.y > lox) & (q2.y < hix) &
                         (q2.z > loy) & (q2.z < hiy) &
                         (q2.w > loz) & (q2.w < hiz);

        const unsigned long long m0 = __ballot(in0);
        const unsigned long long m1 = __ballot(in1);
        const unsigned long long m2 = __ballot(in2);
        const unsigned long long m3 = __ballot(in3);
        const int c0 = __popcll(m0), c1 = __popcll(m1);
        const int c2 = __popcll(m2), c3 = __popcll(m3);

        int base = 0;
        if (lane == 0) base = atomicAdd(&s_count, c0 + c1 + c2 + c3);
        base = __shfl(base, 0);

        const unsigned long long below = (lane == 63)
            ? 0xFFFFFFFFFFFFFFFFull >> 1
            : ((1ull << lane) - 1);
        if (in0) s_idx[base + __popcll(m0 & below)] = n0 + 0;
        if (in1) s_idx[base + c0 + __popcll(m1 & below)] = n0 + 1;
        if (in2) s_idx[base + c0 + c1 + __popcll(m2 & below)] = n0 + 2;
        if (in3) s_idx[base + c0 + c1 + c2 + __popcll(m3 & below)] = n0 + 3;
    }
    __syncthreads();
    const int count = s_count;

    // pad so the gather always runs full 8-deep batches (dupes harmless)
    if (count > 0 && tid < PAD) s_idx[count + tid] = s_idx[0];
    __syncthreads();

    // ---- phase 2: gather-max. wave w owns rows w, w+16, ...; lane l covers
    // channels [4l,4l+4) -> one full 1KB row per wave-instruction ----
    const float* fb = feats + (size_t)b * Nn * Cn;
    float4 mx = make_float4(-INFINITY, -INFINITY, -INFINITY, -INFINITY);
    for (int i = w; i < count; i += 8 * NW) {
        const int a0 = s_idx[i + 0 * NW], a1 = s_idx[i + 1 * NW];
        const int a2 = s_idx[i + 2 * NW], a3 = s_idx[i + 3 * NW];
        const int a4 = s_idx[i + 4 * NW], a5 = s_idx[i + 5 * NW];
        const int a6 = s_idx[i + 6 * NW], a7 = s_idx[i + 7 * NW];
        const float4 f0 = *(const float4*)(fb + (size_t)a0 * Cn + lane * 4);
        const float4 f1 = *(const float4*)(fb + (size_t)a1 * Cn + lane * 4);
        const float4 f2 = *(const float4*)(fb + (size_t)a2 * Cn + lane * 4);
        const float4 f3 = *(const float4*)(fb + (size_t)a3 * Cn + lane * 4);
        const float4 f4 = *(const float4*)(fb + (size_t)a4 * Cn + lane * 4);
        const float4 f5 = *(const float4*)(fb + (size_t)a5 * Cn + lane * 4);
        const float4 f6 = *(const float4*)(fb + (size_t)a6 * Cn + lane * 4);
        const float4 f7 = *(const float4*)(fb + (size_t)a7 * Cn + lane * 4);
        mx = max4(mx, max4(max4(f0, f1), max4(f2, f3)));
        mx = max4(mx, max4(max4(f4, f5), max4(f6, f7)));
    }
    *(float4*)&s_part[w][lane * 4] = mx;
    __syncthreads();

    // ---- phase 3: reduce 16 wave-partials, write (keep -inf sentinel) ----
    if (tid < Cn) {
        float m = s_part[0][tid];
        #pragma unroll
        for (int k = 1; k < NW; ++k) m = fmaxf(m, s_part[k][tid]);
        partial[(size_t)blk * Cn + tid] = m;
    }
}

// ---------------- Kernel 2: combine halves + 2-layer MLP ------------------
// grid = 128 blocks x 1024 thr, proven c-split-4 MLP (R2 structure).
__global__ __launch_bounds__(BT) void reduce_mlp_kernel(
    const float* __restrict__ partial,     // (256, 256)
    const float* __restrict__ W1,          // (C,256)
    const float* __restrict__ b1,
    const float* __restrict__ W2,          // (256,256)
    const float* __restrict__ b2,
    float* __restrict__ out)               // (B,K,256)
{
    const int bk  = blockIdx.x;
    const int tid = threadIdx.x;
    const int g   = tid >> 8;              // 0..3
    const int d   = tid & 255;

    __shared__ float s_vec[Cn];
    __shared__ float s_red[4][Cn];

    if (tid < Cn) {
        float m = fmaxf(partial[(size_t)(2 * bk) * Cn + tid],
                        partial[(size_t)(2 * bk + 1) * Cn + tid]);
        if (m == -INFINITY) m = 0.0f;      // empty box -> 0
        s_vec[tid] = m;
    }
    __syncthreads();

    // layer 1, c-split 4 ways (chain length 64)
    {
        const float* w1 = W1 + (size_t)(g * 64) * 256 + d;
        const float* sv = s_vec + g * 64;
        float acc = 0.0f;
        #pragma unroll 16
        for (int c = 0; c < 64; ++c)
            acc = fmaf(sv[c], w1[(size_t)c * 256], acc);
        s_red[g][d] = acc;
    }
    __syncthreads();
    if (tid < Cn) {
        s_vec[tid] = fmaxf(
            b1[tid] + ((s_red[0][tid] + s_red[1][tid]) +
                       (s_red[2][tid] + s_red[3][tid])), 0.0f);
    }
    __syncthreads();

    // layer 2
    {
        const float* w2 = W2 + (size_t)(g * 64) * 256 + d;
        const float* sv = s_vec + g * 64;
        float acc = 0.0f;
        #pragma unroll 16
        for (int c = 0; c < 64; ++c)
            acc = fmaf(sv[c], w2[(size_t)c * 256], acc);
        s_red[g][d] = acc;
    }
    __syncthreads();
    if (tid < Cn) {
        out[(size_t)bk * 256 + tid] = fmaxf(
            b2[tid] + ((s_red[0][tid] + s_red[1][tid]) +
                       (s_red[2][tid] + s_red[3][tid])), 0.0f);
    }
}

extern "C" void kernel_launch(void* const* d_in, const int* in_sizes, int n_in,
                              void* d_out, int out_size, void* d_ws, size_t ws_size,
                              hipStream_t stream) {
    const float* points    = (const float*)d_in[0];
    const float* feats     = (const float*)d_in[1];
    const float* proposals = (const float*)d_in[2];
    const float* W1        = (const float*)d_in[3];
    const float* b1        = (const float*)d_in[4];
    const float* W2        = (const float*)d_in[5];
    const float* b2        = (const float*)d_in[6];
    float* out             = (float*)d_out;
    float* partial         = (float*)d_ws;         // 256*256*4 = 256 KB

    pool_half_kernel<<<2 * BK, BT, 0, stream>>>(points, feats, proposals,
                                                partial);
    reduce_mlp_kernel<<<BK, BT, 0, stream>>>(partial, W1, b1, W2, b2, out);
}

// Round 7
// 78.704 us; speedup vs baseline: 1.0822x; 1.0493x over previous
//
#include <hip/hip_runtime.h>

#define Bn 2
#define Nn 4096
#define Cn 256
#define Kn 64
#define BK (Bn * Kn)
#define NSEG 8                 // eighths of N per box
#define SEGN (Nn / NSEG)       // 512 points per k1 block
#define NB1 (BK * NSEG)        // 1024 k1 blocks
#define W1T 4                  // waves per k1 block
#define PAD1 (7 * W1T)         // gather batch over-read padding

__device__ __forceinline__ float4 max4(float4 a, float4 b) {
    return make_float4(fmaxf(a.x, b.x), fmaxf(a.y, b.y),
                       fmaxf(a.z, b.z), fmaxf(a.w, b.w));
}

// ---------------- Kernel 1: (box, eighth) -> 256-float pooled partial -----
// 1024 small blocks (256 thr, ~6 KB LDS) -> 4 blocks/CU: four independent
// scan->gather phase-chains per CU so cold-HBM gather latency of one block
// overlaps scan/compact/reduce of the others.
__global__ __launch_bounds__(256) void pool_seg_kernel(
    const float* __restrict__ points,      // (B,N,3)
    const float* __restrict__ feats,       // (B,N,C)
    const float* __restrict__ proposals,   // (B,K,7)
    float* __restrict__ partial)           // (NB1, 256): -inf when empty
{
    const int blk  = blockIdx.x;
    const int bk   = blk >> 3;             // box 0..127
    const int seg  = blk & 7;              // eighth 0..7
    const int b    = bk / Kn;
    const int tid  = threadIdx.x;
    const int w    = tid >> 6;             // wave 0..3
    const int lane = tid & 63;

    __shared__ int   s_idx[SEGN + PAD1];   // 2.2 KB
    __shared__ int   s_count;
    __shared__ float s_part[W1T][Cn];      // 4 KB

    // ---- box bounds ----
    const float* prop = proposals + (size_t)bk * 7;
    const float cx = prop[0], cy = prop[1], cz = prop[2];
    const float hx = prop[3] * 0.5f, hy = prop[4] * 0.5f, hz = prop[5] * 0.5f;
    const float lox = cx - hx, loy = cy - hy, loz = cz - hz;
    const float hix = cx + hx, hiy = cy + hy, hiz = cz + hz;

    if (tid == 0) s_count = 0;
    __syncthreads();

    // ---- phase 1: scan this eighth's 512 points. Threads 0..127 own 4
    // points each via 3 float4 loads; wave-aggregated ballot compaction.
    if (tid < 128) {
        const int n0 = seg * SEGN + 4 * tid;
        const float4* pv = (const float4*)(points + (size_t)b * Nn * 3
                                           + (size_t)seg * SEGN * 3);
        const float4 q0 = pv[3 * tid + 0];   // x0 y0 z0 x1
        const float4 q1 = pv[3 * tid + 1];   // y1 z1 x2 y2
        const float4 q2 = pv[3 * tid + 2];   // z2 x3 y3 z3

        const bool in0 = (q0.x > lox) & (q0.x < hix) &
                         (q0.y > loy) & (q0.y < hiy) &
                         (q0.z > loz) & (q0.z < hiz);
        const bool in1 = (q0.w > lox) & (q0.w < hix) &
                         (q1.x > loy) & (q1.x < hiy) &
                         (q1.y > loz) & (q1.y < hiz);
        const bool in2 = (q1.z > lox) & (q1.z < hix) &
                         (q1.w > loy) & (q1.w < hiy) &
                         (q2.x > loz) & (q2.x < hiz);
        const bool in3 = (q2.y > lox) & (q2.y < hix) &
                         (q2.z > loy) & (q2.z < hiy) &
                         (q2.w > loz) & (q2.w < hiz);

        const unsigned long long m0 = __ballot(in0);
        const unsigned long long m1 = __ballot(in1);
        const unsigned long long m2 = __ballot(in2);
        const unsigned long long m3 = __ballot(in3);
        const int c0 = __popcll(m0), c1 = __popcll(m1);
        const int c2 = __popcll(m2), c3 = __popcll(m3);

        int base = 0;
        if (lane == 0) base = atomicAdd(&s_count, c0 + c1 + c2 + c3);
        base = __shfl(base, 0);

        const unsigned long long below = (lane == 63)
            ? 0xFFFFFFFFFFFFFFFFull >> 1
            : ((1ull << lane) - 1);
        if (in0) s_idx[base + __popcll(m0 & below)] = n0 + 0;
        if (in1) s_idx[base + c0 + __popcll(m1 & below)] = n0 + 1;
        if (in2) s_idx[base + c0 + c1 + __popcll(m2 & below)] = n0 + 2;
        if (in3) s_idx[base + c0 + c1 + c2 + __popcll(m3 & below)] = n0 + 3;
    }
    __syncthreads();
    const int count = s_count;

    // pad so the gather always runs full 8-deep batches (dupes harmless)
    if (count > 0 && tid < PAD1) s_idx[count + tid] = s_idx[0];
    __syncthreads();

    // ---- phase 2: gather-max. wave w owns list slots w, w+4, ...; lane l
    // covers channels [4l,4l+4) -> one full 1KB row per wave-instruction ----
    const float* fb = feats + (size_t)b * Nn * Cn;
    float4 mx = make_float4(-INFINITY, -INFINITY, -INFINITY, -INFINITY);
    for (int i = w; i < count; i += 8 * W1T) {
        const int a0 = s_idx[i + 0 * W1T], a1 = s_idx[i + 1 * W1T];
        const int a2 = s_idx[i + 2 * W1T], a3 = s_idx[i + 3 * W1T];
        const int a4 = s_idx[i + 4 * W1T], a5 = s_idx[i + 5 * W1T];
        const int a6 = s_idx[i + 6 * W1T], a7 = s_idx[i + 7 * W1T];
        const float4 f0 = *(const float4*)(fb + (size_t)a0 * Cn + lane * 4);
        const float4 f1 = *(const float4*)(fb + (size_t)a1 * Cn + lane * 4);
        const float4 f2 = *(const float4*)(fb + (size_t)a2 * Cn + lane * 4);
        const float4 f3 = *(const float4*)(fb + (size_t)a3 * Cn + lane * 4);
        const float4 f4 = *(const float4*)(fb + (size_t)a4 * Cn + lane * 4);
        const float4 f5 = *(const float4*)(fb + (size_t)a5 * Cn + lane * 4);
        const float4 f6 = *(const float4*)(fb + (size_t)a6 * Cn + lane * 4);
        const float4 f7 = *(const float4*)(fb + (size_t)a7 * Cn + lane * 4);
        mx = max4(mx, max4(max4(f0, f1), max4(f2, f3)));
        mx = max4(mx, max4(max4(f4, f5), max4(f6, f7)));
    }
    *(float4*)&s_part[w][lane * 4] = mx;
    __syncthreads();

    // ---- phase 3: reduce 4 wave-partials, write (keep -inf sentinel) ----
    // 256 threads cover the 256 channels exactly.
    {
        float m = fmaxf(fmaxf(s_part[0][tid], s_part[1][tid]),
                        fmaxf(s_part[2][tid], s_part[3][tid]));
        partial[(size_t)blk * Cn + tid] = m;
    }
}

// ---------------- Kernel 2: combine 8 partials + 2-layer MLP --------------
// grid = 128 blocks x 1024 thr, proven c-split-4 MLP (R2 structure).
__global__ __launch_bounds__(1024) void reduce_mlp_kernel(
    const float* __restrict__ partial,     // (NB1, 256)
    const float* __restrict__ W1,          // (C,256)
    const float* __restrict__ b1,
    const float* __restrict__ W2,          // (256,256)
    const float* __restrict__ b2,
    float* __restrict__ out)               // (B,K,256)
{
    const int bk  = blockIdx.x;
    const int tid = threadIdx.x;
    const int g   = tid >> 8;              // 0..3
    const int d   = tid & 255;

    __shared__ float s_m[4][Cn];
    __shared__ float s_vec[Cn];
    __shared__ float s_red[4][Cn];

    // each group reduces 2 of the box's 8 partials
    {
        const float* pp = partial + ((size_t)bk * NSEG) * Cn + d;
        const float a = pp[(size_t)(2 * g + 0) * Cn];
        const float c = pp[(size_t)(2 * g + 1) * Cn];
        s_m[g][d] = fmaxf(a, c);
    }
    __syncthreads();

    if (tid < Cn) {
        float m = fmaxf(fmaxf(s_m[0][tid], s_m[1][tid]),
                        fmaxf(s_m[2][tid], s_m[3][tid]));
        if (m == -INFINITY) m = 0.0f;      // empty box -> 0
        s_vec[tid] = m;
    }
    __syncthreads();

    // layer 1, c-split 4 ways (chain length 64)
    {
        const float* w1 = W1 + (size_t)(g * 64) * 256 + d;
        const float* sv = s_vec + g * 64;
        float acc = 0.0f;
        #pragma unroll 16
        for (int c = 0; c < 64; ++c)
            acc = fmaf(sv[c], w1[(size_t)c * 256], acc);
        s_red[g][d] = acc;
    }
    __syncthreads();
    if (tid < Cn) {
        s_vec[tid] = fmaxf(
            b1[tid] + ((s_red[0][tid] + s_red[1][tid]) +
                       (s_red[2][tid] + s_red[3][tid])), 0.0f);
    }
    __syncthreads();

    // layer 2
    {
        const float* w2 = W2 + (size_t)(g * 64) * 256 + d;
        const float* sv = s_vec + g * 64;
        float acc = 0.0f;
        #pragma unroll 16
        for (int c = 0; c < 64; ++c)
            acc = fmaf(sv[c], w2[(size_t)c * 256], acc);
        s_red[g][d] = acc;
    }
    __syncthreads();
    if (tid < Cn) {
        out[(size_t)bk * 256 + tid] = fmaxf(
            b2[tid] + ((s_red[0][tid] + s_red[1][tid]) +
                       (s_red[2][tid] + s_red[3][tid])), 0.0f);
    }
}

extern "C" void kernel_launch(void* const* d_in, const int* in_sizes, int n_in,
                              void* d_out, int out_size, void* d_ws, size_t ws_size,
                              hipStream_t stream) {
    const float* points    = (const float*)d_in[0];
    const float* feats     = (const float*)d_in[1];
    const float* proposals = (const float*)d_in[2];
    const float* W1        = (const float*)d_in[3];
    const float* b1        = (const float*)d_in[4];
    const float* W2        = (const float*)d_in[5];
    const float* b2        = (const float*)d_in[6];
    float* out             = (float*)d_out;
    float* partial         = (float*)d_ws;         // 1024*256*4 = 1 MB

    pool_seg_kernel<<<NB1, 256, 0, stream>>>(points, feats, proposals,
                                             partial);
    reduce_mlp_kernel<<<BK, 1024, 0, stream>>>(partial, W1, b1, W2, b2, out);
}